// Round 1
// baseline (855.979 us; speedup 1.0000x reference)
//
#include <hip/hip_runtime.h>
#include <math.h>

// Problem constants
#define TT 8
#define FN 2304          // 48*48
#define FL 1024          // C*S*S
#define HS 48

// ---------------- workspace layout (bytes) ----------------
static constexpr size_t OFF_IDX1T  = 0;           // 75,497,472 (region A)
static constexpr size_t OFF_SEL    = 0;           // alias A after k_tk: 28,311,552
static constexpr size_t OFF_FINPUT = 28311552;    // alias A: 28,904,448
static constexpr size_t OFF_WT     = 57216000;    // alias A: 442,368
static constexpr size_t OFF_TK     = 75497472;    // 75,497,472
static constexpr size_t OFF_CN     = 150994944;   // 9,437,184
static constexpr size_t OFF_QH     = 160432128;   // 4,718,592
static constexpr size_t OFF_SRCMAP = 165150720;   // 73,728
static constexpr size_t OFF_BSRC   = 165224448;   // 1,179,648
static constexpr size_t OFF_BW     = 166404096;   // 1,179,648
static constexpr size_t OFF_CSOFT  = 167583744;   // 9,216
static constexpr size_t OFF_CIDX   = 167592960;   // 9,216
static constexpr size_t OFF_CSRC   = 167602176;   // 147,456
static constexpr size_t OFF_CW     = 167749632;   // 147,456  -> total 167,897,088

// ---------------- K0: nearest-neighbor source map ----------------
__global__ void k_nearmap(const float* __restrict__ loc, int* __restrict__ srcmap) {
  int idx = blockIdx.x * 256 + threadIdx.x;
  if (idx >= TT * FN) return;
  int t = idx / FN, f = idx % FN;
  float lx = loc[(size_t)(t * 2 + 0) * FN + f];
  float ly = loc[(size_t)(t * 2 + 1) * FN + f];
  // exact reference op order
  float gx = 2.0f * lx / 47.0f - 1.0f;
  float gy = 2.0f * ly / 47.0f - 1.0f;
  float ix = (gx + 1.0f) * 0.5f * 47.0f;
  float iy = (gy + 1.0f) * 0.5f * 47.0f;
  int ixn = __float2int_rn(ix);   // round-half-even == jnp.round
  int iyn = __float2int_rn(iy);
  bool valid = (ixn >= 0) && (ixn < 48) && (iyn >= 0) && (iyn < 48);
  srcmap[idx] = valid ? (iyn * 48 + ixn) : -1;
}

// ---------------- K1: transpose idx1 (t,cl,f) -> (t,f,cl) ----------------
__global__ __launch_bounds__(256) void k_transpose(const float* __restrict__ in, float* __restrict__ out) {
  __shared__ float tile[32][33];
  int t = blockIdx.z;
  int cl0 = blockIdx.x * 32;
  int f0 = blockIdx.y * 32;
  const float* src = in + (size_t)t * FL * FN;
  float* dst = out + (size_t)t * FN * FL;
  int tx = threadIdx.x, ty = threadIdx.y; // 32 x 8
#pragma unroll
  for (int k = 0; k < 4; k++)
    tile[ty + 8 * k][tx] = src[(size_t)(cl0 + ty + 8 * k) * FN + f0 + tx];
  __syncthreads();
#pragma unroll
  for (int k = 0; k < 4; k++)
    dst[(size_t)(f0 + ty + 8 * k) * FL + cl0 + tx] = tile[tx][ty + 8 * k];
}

// ---------------- K2: gather + L2-normalize -> tk (t,f,cl) ----------------
__global__ __launch_bounds__(256) void k_tk(const float* __restrict__ idx1t,
                                            const int* __restrict__ srcmap,
                                            float* __restrict__ tk) {
  __shared__ float red[4];
  int bid = blockIdx.x;           // t*FN + f_dst
  int t = bid / FN;
  int s = srcmap[bid];
  float* dst = tk + (size_t)bid * FL;
  int tid = threadIdx.x;
  if (s < 0) {                    // block-uniform branch
#pragma unroll
    for (int k = 0; k < 4; k++) dst[tid + 256 * k] = 0.f;
    return;
  }
  const float* row = idx1t + ((size_t)t * FN + s) * FL;
  float v[4];
  float sq = 0.f;
#pragma unroll
  for (int k = 0; k < 4; k++) { v[k] = row[tid + 256 * k]; sq += v[k] * v[k]; }
#pragma unroll
  for (int m = 1; m <= 32; m <<= 1) sq += __shfl_xor(sq, m, 64);
  int lane = tid & 63, w = tid >> 6;
  if (lane == 0) red[w] = sq;
  __syncthreads();
  float total = red[0] + red[1] + red[2] + red[3];
  float scale = 1.0f / fmaxf(sqrtf(total), 1e-12f);
#pragma unroll
  for (int k = 0; k < 4; k++) dst[tid + 256 * k] = v[k] * scale;
}

// ---------------- K3: unfold curr_feat + L2-normalize -> cn (f,cl) ----------------
__global__ __launch_bounds__(256) void k_cn(const float* __restrict__ cf, float* __restrict__ cn) {
  __shared__ float red[4];
  int f = blockIdx.x;             // i*48+j
  int i = f / 48, j = f % 48;
  int tid = threadIdx.x;
  float v[4];
  float sq = 0.f;
#pragma unroll
  for (int k = 0; k < 4; k++) {
    int cl = tid + 256 * k;
    int c = cl >> 4, sy = (cl >> 2) & 3, sx = cl & 3;
    v[k] = cf[(size_t)c * 36864 + (size_t)(i * 4 + sy) * 192 + (j * 4 + sx)];
    sq += v[k] * v[k];
  }
#pragma unroll
  for (int m = 1; m <= 32; m <<= 1) sq += __shfl_xor(sq, m, 64);
  int lane = tid & 63, w = tid >> 6;
  if (lane == 0) red[w] = sq;
  __syncthreads();
  float total = red[0] + red[1] + red[2] + red[3];
  float scale = 1.0f / fmaxf(sqrtf(total), 1e-12f);
#pragma unroll
  for (int k = 0; k < 4; k++) cn[(size_t)f * FL + tid + 256 * k] = v[k] * scale;
}

// ---------------- K4: q-half grouped 5x5 conv (t-invariant, per g) ----------------
__global__ __launch_bounds__(128) void k_qconv(const float* __restrict__ cn,
                                               const float* __restrict__ wtdw,
                                               const float* __restrict__ btdw,
                                               float* __restrict__ qhalf) {
  const int xt = blockIdx.x, y = blockIdx.y, g = blockIdx.z;
  const int j = threadIdx.x;      // output channel 0..127
  const int x0 = xt * 16;
  float w0[25], w1[25];
  {
    const float* wp = wtdw + (size_t)j * 50;
#pragma unroll
    for (int p = 0; p < 25; ++p) { w0[p] = wp[p]; w1[p] = wp[25 + p]; }
  }
  float acc[16];
#pragma unroll
  for (int i = 0; i < 16; ++i) acc[i] = 0.f;
  const int cbase = g * 256 + 2 * j;
#pragma unroll
  for (int r = 0; r < 5; ++r) {
    const int yy = y - 2 + r;
    if (yy < 0 || yy >= 48) continue;
#pragma unroll
    for (int cc2 = 0; cc2 < 20; ++cc2) {
      const int xx = x0 - 2 + cc2;
      float vx = 0.f, vy = 0.f;
      if (xx >= 0 && xx < 48) {
        const float2 v = *reinterpret_cast<const float2*>(cn + ((size_t)(yy * 48 + xx) << 10) + cbase);
        vx = v.x; vy = v.y;
      }
#pragma unroll
      for (int kx = 0; kx < 5; ++kx) {
        const int xo = cc2 - kx;
        if (xo >= 0 && xo < 16)
          acc[xo] = fmaf(vx, w0[r * 5 + kx], fmaf(vy, w1[r * 5 + kx], acc[xo]));
      }
    }
  }
  const float bb = btdw[j];
#pragma unroll
  for (int xo = 0; xo < 16; ++xo)
    qhalf[((size_t)g * FN + (y * 48 + x0 + xo)) * 128 + j] = acc[xo] + bb;
}

// ---------------- K5: k-half conv + LN + GELU + 1x1 + tanh + refpts -> bilinear maps ----------------
__global__ __launch_bounds__(128) void k_kconv_ln(const float* __restrict__ tk,
                                                  const float* __restrict__ wtdw,
                                                  const float* __restrict__ btdw,
                                                  const float* __restrict__ qhalf,
                                                  const float* __restrict__ lng,
                                                  const float* __restrict__ lnb,
                                                  const float* __restrict__ wtpw,
                                                  int* __restrict__ bsrc,
                                                  float* __restrict__ bw) {
  __shared__ float ch[16][257];
  const int xt = blockIdx.x, y = blockIdx.y, b = blockIdx.z;
  const int t = b >> 2, g = b & 3;
  const int j = threadIdx.x;      // output channel 128+j
  const int x0 = xt * 16;
  float w0[25], w1[25];
  {
    const float* wp = wtdw + (size_t)(128 + j) * 50;
#pragma unroll
    for (int p = 0; p < 25; ++p) { w0[p] = wp[p]; w1[p] = wp[25 + p]; }
  }
  float acc[16];
#pragma unroll
  for (int i = 0; i < 16; ++i) acc[i] = 0.f;
  const size_t tbase = (size_t)t * FN;
  const int cbase = g * 256 + 2 * j;
#pragma unroll
  for (int r = 0; r < 5; ++r) {
    const int yy = y - 2 + r;
    if (yy < 0 || yy >= 48) continue;
#pragma unroll
    for (int cc2 = 0; cc2 < 20; ++cc2) {
      const int xx = x0 - 2 + cc2;
      float vx = 0.f, vy = 0.f;
      if (xx >= 0 && xx < 48) {
        const float2 v = *reinterpret_cast<const float2*>(tk + ((tbase + yy * 48 + xx) << 10) + cbase);
        vx = v.x; vy = v.y;
      }
#pragma unroll
      for (int kx = 0; kx < 5; ++kx) {
        const int xo = cc2 - kx;
        if (xo >= 0 && xo < 16)
          acc[xo] = fmaf(vx, w0[r * 5 + kx], fmaf(vy, w1[r * 5 + kx], acc[xo]));
      }
    }
  }
  const float bb = btdw[128 + j];
#pragma unroll
  for (int xo = 0; xo < 16; ++xo) ch[xo][128 + j] = acc[xo] + bb;
#pragma unroll
  for (int xo = 0; xo < 16; ++xo)
    ch[xo][j] = qhalf[((size_t)g * FN + (y * 48 + x0 + xo)) * 128 + j];
  __syncthreads();

  const int lane = j & 63, wv = j >> 6;
  for (int p = wv; p < 16; p += 2) {
    float v0 = ch[p][lane], v1 = ch[p][lane + 64], v2 = ch[p][lane + 128], v3 = ch[p][lane + 192];
    float s = v0 + v1 + v2 + v3;
    float q = v0 * v0 + v1 * v1 + v2 * v2 + v3 * v3;
#pragma unroll
    for (int m = 1; m <= 32; m <<= 1) { s += __shfl_xor(s, m, 64); q += __shfl_xor(q, m, 64); }
    float mean = s * (1.0f / 256.0f);
    float var = q * (1.0f / 256.0f) - mean * mean;
    float rstd = rsqrtf(var + 1e-5f);
    float d0 = 0.f, d1 = 0.f;
#pragma unroll
    for (int k2 = 0; k2 < 4; k2++) {
      int c = lane + 64 * k2;
      float xv = (k2 == 0) ? v0 : (k2 == 1) ? v1 : (k2 == 2) ? v2 : v3;
      float xn = (xv - mean) * rstd * lng[c] + lnb[c];
      float ge = 0.5f * xn * (1.0f + erff(xn * 0.70710678118654752440f));
      d0 += ge * wtpw[c];
      d1 += ge * wtpw[256 + c];
    }
#pragma unroll
    for (int m = 1; m <= 32; m <<= 1) { d0 += __shfl_xor(d0, m, 64); d1 += __shfl_xor(d1, m, 64); }
    if (lane == 0) {
      float o0 = tanhf(d0) * (2.0f / 48.0f);
      float o1 = tanhf(d1) * (2.0f / 48.0f);
      int x = x0 + p;
      float ry = (0.5f + (float)y) / 48.0f * 2.0f - 1.0f;
      float rx = (0.5f + (float)x) / 48.0f * 2.0f - 1.0f;
      float pos0 = o0 + ry, pos1 = o1 + rx;   // gp = reversed
      float ix = (pos1 + 1.0f) * 0.5f * 47.0f;
      float iy = (pos0 + 1.0f) * 0.5f * 47.0f;
      float x0f = floorf(ix), y0f = floorf(iy);
      float wx = ix - x0f, wy = iy - y0f;
      int xi = (int)x0f, yi = (int)y0f;
      size_t base = ((size_t)b * FN + y * 48 + x) * 4;
#pragma unroll
      for (int c = 0; c < 4; c++) {
        int dy = c >> 1, dx = c & 1;
        int yy2 = yi + dy, xx2 = xi + dx;
        bool ok = ((unsigned)yy2 < 48u) && ((unsigned)xx2 < 48u);
        float wgt = (dy ? wy : 1.0f - wy) * (dx ? wx : 1.0f - wx);
        bsrc[base + c] = ok ? (yy2 * 48 + xx2) : -1;
        bw[base + c] = wgt;
      }
    }
  }
}

// ---------------- K6: mat einsum + max/argmax over t ----------------
__global__ __launch_bounds__(256) void k_mat(const float* __restrict__ tk,
                                             const float* __restrict__ cn,
                                             const int* __restrict__ bsrc,
                                             const float* __restrict__ bw,
                                             float* __restrict__ csoft,
                                             int* __restrict__ cidx) {
  __shared__ float cnrow[1024];
  __shared__ float red[4];
  int f = blockIdx.x;
  int tid = threadIdx.x;
#pragma unroll
  for (int k = 0; k < 4; k++) cnrow[tid + 256 * k] = cn[(size_t)f * FL + tid + 256 * k];
  __syncthreads();
  float bestv = -INFINITY;
  int besti = 0;
  for (int t = 0; t < TT; t++) {
    float partial = 0.f;
#pragma unroll
    for (int gg = 0; gg < 4; gg++) {
      int b = t * 4 + gg;
      size_t mb = ((size_t)b * FN + f) * 4;
      float v = 0.f;
#pragma unroll
      for (int c = 0; c < 4; c++) {
        int s = bsrc[mb + c];
        if (s >= 0) v += bw[mb + c] * tk[((size_t)t * FN + s) * FL + gg * 256 + tid];
      }
      partial += cnrow[gg * 256 + tid] * v;
    }
#pragma unroll
    for (int m = 1; m <= 32; m <<= 1) partial += __shfl_xor(partial, m, 64);
    int lane = tid & 63, w = tid >> 6;
    if (lane == 0) red[w] = partial;
    __syncthreads();
    if (tid == 0) {
      float tot = red[0] + red[1] + red[2] + red[3];
      if (tot > bestv) { bestv = tot; besti = t; }
    }
    __syncthreads();
  }
  if (tid == 0) { csoft[f] = bestv; cidx[f] = besti; }
}

// ---------------- K7: compose bilinear corners with nearest map at t=cidx ----------------
__global__ void k_comp(const int* __restrict__ bsrc, const float* __restrict__ bw,
                       const int* __restrict__ cidx, const int* __restrict__ srcmap,
                       int* __restrict__ csrc, float* __restrict__ cw) {
  int idx = blockIdx.x * 256 + threadIdx.x;  // f*4+g
  if (idx >= FN * 4) return;
  int f = idx >> 2, g = idx & 3;
  int t = cidx[f];
  int b = t * 4 + g;
  size_t mb = ((size_t)b * FN + f) * 4;
  size_t ob = (size_t)idx * 4;
#pragma unroll
  for (int c = 0; c < 4; c++) {
    int s = bsrc[mb + c];
    csrc[ob + c] = (s >= 0) ? srcmap[t * FN + s] : -1;
    cw[ob + c] = bw[mb + c];
  }
}

// ---------------- K8: fused nearest+bilinear+select of sparse sets ----------------
__global__ __launch_bounds__(256) void k_sel(const float* __restrict__ s1,
                                             const float* __restrict__ s2,
                                             const float* __restrict__ s3,
                                             const int* __restrict__ cidx,
                                             const int* __restrict__ csrc,
                                             const float* __restrict__ cw,
                                             float* __restrict__ sel) {
  __shared__ float pl[4 * FN];   // 4 t-planes of this channel
  int cl = blockIdx.x, m = blockIdx.y;
  const float* sm = (m == 0) ? s1 : (m == 1) ? s2 : s3;
  int g = cl >> 8;
  int tid = threadIdx.x;
  float acc[9];
  int tsel[9];
  int4 cs[9];
  float4 wv[9];
#pragma unroll
  for (int it = 0; it < 9; it++) {
    int f = tid + 256 * it;
    tsel[it] = cidx[f];
    cs[it] = *reinterpret_cast<const int4*>(csrc + ((size_t)f * 4 + g) * 4);
    wv[it] = *reinterpret_cast<const float4*>(cw + ((size_t)f * 4 + g) * 4);
    acc[it] = 0.f;
  }
  for (int half = 0; half < 2; half++) {
    __syncthreads();
    for (int i = tid; i < 4 * FN; i += 256) {
      int t = i / FN + half * 4;
      pl[i] = sm[((size_t)t * FL + cl) * FN + (i % FN)];
    }
    __syncthreads();
#pragma unroll
    for (int it = 0; it < 9; it++) {
      int t = tsel[it] - half * 4;
      if (t >= 0 && t < 4) {
        float a = 0.f;
        if (cs[it].x >= 0) a += wv[it].x * pl[t * FN + cs[it].x];
        if (cs[it].y >= 0) a += wv[it].y * pl[t * FN + cs[it].y];
        if (cs[it].z >= 0) a += wv[it].z * pl[t * FN + cs[it].z];
        if (cs[it].w >= 0) a += wv[it].w * pl[t * FN + cs[it].w];
        acc[it] = a;
      }
    }
  }
#pragma unroll
  for (int it = 0; it < 9; it++)
    sel[((size_t)m * FL + cl) * FN + tid + 256 * it] = acc[it];
}

// ---------------- K9: fold + concat into padded conv input (192,194,194) ----------------
__global__ void k_fold(const float* __restrict__ sel, float* __restrict__ finp) {
  int idx = blockIdx.x * 256 + threadIdx.x;
  if (idx >= 192 * 194 * 194) return;
  int ci = idx / (194 * 194);
  int r = idx % (194 * 194);
  int yy = r / 194, xx = r % 194;
  int Y = yy - 1, X = xx - 1;
  float v = 0.f;
  if ((unsigned)Y < 192u && (unsigned)X < 192u) {
    int m = ci >> 6, c2 = ci & 63;
    int cl = c2 * 16 + (Y & 3) * 4 + (X & 3);
    int f = (Y >> 2) * 48 + (X >> 2);
    v = sel[((size_t)m * FL + cl) * FN + f];
  }
  finp[idx] = v;
}

// ---------------- K9b: transpose w_fus (co,ci,k) -> (ci,k,co) ----------------
__global__ void k_wt(const float* __restrict__ wfus, float* __restrict__ wt) {
  int idx = blockIdx.x * 256 + threadIdx.x;
  if (idx >= 64 * 192 * 9) return;
  int co = idx / (192 * 9);
  int r = idx % (192 * 9);
  int ci = r / 9, k = r % 9;
  wt[((size_t)ci * 9 + k) * 64 + co] = wfus[idx];
}

// ---------------- K10: 3x3 fusion conv + *csoft_f + af ----------------
__global__ __launch_bounds__(256) void k_fus(const float* __restrict__ finp,
                                             const float* __restrict__ wt,
                                             const float* __restrict__ bfus,
                                             const float* __restrict__ csoft,
                                             const float* __restrict__ af,
                                             float* __restrict__ out) {
  __shared__ float in_t[16][10][36];
  __shared__ float ws_[16][9][16];
  const int X0 = blockIdx.x * 32, Y0 = blockIdx.y * 8, co0 = blockIdx.z * 16;
  const int tid = threadIdx.x;
  const int cog = tid >> 6;           // 4 co per thread: co0 + cog*4 + c
  const int pg = tid & 63;
  const int px0 = (pg & 7) * 4, py = pg >> 3;   // 4 x-positions per thread
  float acc[4][4];
#pragma unroll
  for (int a = 0; a < 4; a++)
#pragma unroll
    for (int b = 0; b < 4; b++) acc[a][b] = 0.f;

  for (int ci0 = 0; ci0 < 192; ci0 += 16) {
    __syncthreads();
    for (int i = tid; i < 16 * 10 * 34; i += 256) {
      int ci = i / 340;
      int rr = i % 340;
      int rrow = rr / 34, ccol = rr % 34;
      in_t[ci][rrow][ccol] = finp[((size_t)(ci0 + ci) * 194 + (Y0 + rrow)) * 194 + X0 + ccol];
    }
    for (int i = tid; i < 16 * 9 * 16; i += 256) {
      int co = i & 15;
      int k = (i >> 4) % 9;
      int ci = i / 144;
      ws_[ci][k][co] = wt[((size_t)(ci0 + ci) * 9 + k) * 64 + co0 + co];
    }
    __syncthreads();
    for (int ci = 0; ci < 16; ci++) {
#pragma unroll
      for (int ky = 0; ky < 3; ky++) {
        float col[6];
        const float4 c4 = *reinterpret_cast<const float4*>(&in_t[ci][py + ky][px0]);
        const float2 c2 = *reinterpret_cast<const float2*>(&in_t[ci][py + ky][px0 + 4]);
        col[0] = c4.x; col[1] = c4.y; col[2] = c4.z; col[3] = c4.w; col[4] = c2.x; col[5] = c2.y;
#pragma unroll
        for (int kx = 0; kx < 3; kx++) {
          const float4 wv = *reinterpret_cast<const float4*>(&ws_[ci][ky * 3 + kx][cog * 4]);
#pragma unroll
          for (int p = 0; p < 4; p++) {
            acc[0][p] = fmaf(col[p + kx], wv.x, acc[0][p]);
            acc[1][p] = fmaf(col[p + kx], wv.y, acc[1][p]);
            acc[2][p] = fmaf(col[p + kx], wv.z, acc[2][p]);
            acc[3][p] = fmaf(col[p + kx], wv.w, acc[3][p]);
          }
        }
      }
    }
  }
#pragma unroll
  for (int c = 0; c < 4; c++) {
    int co = co0 + cog * 4 + c;
    float bb = bfus[co];
    int Y = Y0 + py;
#pragma unroll
    for (int p = 0; p < 4; p++) {
      int X = X0 + px0 + p;
      float cfv = csoft[(Y >> 2) * 48 + (X >> 2)];
      size_t oi = ((size_t)co * 192 + Y) * 192 + X;
      out[oi] = (acc[c][p] + bb) * cfv + af[oi];
    }
  }
}

// ---------------- launcher ----------------
extern "C" void kernel_launch(void* const* d_in, const int* in_sizes, int n_in,
                              void* d_out, int out_size, void* d_ws, size_t ws_size,
                              hipStream_t stream) {
  const float* cf   = (const float*)d_in[0];
  const float* idx1 = (const float*)d_in[1];
  const float* af   = (const float*)d_in[2];
  const float* s1   = (const float*)d_in[3];
  const float* s2   = (const float*)d_in[4];
  const float* s3   = (const float*)d_in[5];
  const float* loc  = (const float*)d_in[6];
  const float* wtdw = (const float*)d_in[7];
  const float* btdw = (const float*)d_in[8];
  const float* lng  = (const float*)d_in[9];
  const float* lnb  = (const float*)d_in[10];
  const float* wtpw = (const float*)d_in[11];
  const float* wfus = (const float*)d_in[12];
  const float* bfus = (const float*)d_in[13];
  float* out = (float*)d_out;
  char* ws = (char*)d_ws;

  float* idx1t  = (float*)(ws + OFF_IDX1T);
  float* sel    = (float*)(ws + OFF_SEL);
  float* finp   = (float*)(ws + OFF_FINPUT);
  float* wt     = (float*)(ws + OFF_WT);
  float* tk     = (float*)(ws + OFF_TK);
  float* cn     = (float*)(ws + OFF_CN);
  float* qh     = (float*)(ws + OFF_QH);
  int*   srcmap = (int*)(ws + OFF_SRCMAP);
  int*   bsrc   = (int*)(ws + OFF_BSRC);
  float* bw     = (float*)(ws + OFF_BW);
  float* csoft  = (float*)(ws + OFF_CSOFT);
  int*   cidx   = (int*)(ws + OFF_CIDX);
  int*   csrc   = (int*)(ws + OFF_CSRC);
  float* cw     = (float*)(ws + OFF_CW);

  k_nearmap<<<72, 256, 0, stream>>>(loc, srcmap);
  k_transpose<<<dim3(32, 72, 8), dim3(32, 8), 0, stream>>>(idx1, idx1t);
  k_cn<<<2304, 256, 0, stream>>>(cf, cn);
  k_tk<<<18432, 256, 0, stream>>>(idx1t, srcmap, tk);
  k_wt<<<432, 256, 0, stream>>>(wfus, wt);            // after k_tk: aliases idx1t region
  k_qconv<<<dim3(3, 48, 4), 128, 0, stream>>>(cn, wtdw, btdw, qh);
  k_kconv_ln<<<dim3(3, 48, 32), 128, 0, stream>>>(tk, wtdw, btdw, qh, lng, lnb, wtpw, bsrc, bw);
  k_mat<<<2304, 256, 0, stream>>>(tk, cn, bsrc, bw, csoft, cidx);
  k_comp<<<36, 256, 0, stream>>>(bsrc, bw, cidx, srcmap, csrc, cw);
  k_sel<<<dim3(1024, 3), 256, 0, stream>>>(s1, s2, s3, cidx, csrc, cw, sel);
  k_fold<<<28227, 256, 0, stream>>>(sel, finp);
  k_fus<<<dim3(6, 24, 4), 256, 0, stream>>>(finp, wt, bfus, csoft, af, out);
}

// Round 2
// 625.344 us; speedup vs baseline: 1.3688x; 1.3688x over previous
//
#include <hip/hip_runtime.h>
#include <math.h>

// Problem constants
#define TT 8
#define FN 2304          // 48*48
#define FL 1024          // C*S*S
#define HS 48

typedef __attribute__((ext_vector_type(8))) short short8;
typedef __attribute__((ext_vector_type(4))) float floatx4;

// ---------------- workspace layout (bytes) ----------------
static constexpr size_t OFF_IDX1T  = 0;           // 75,497,472 (region A)
static constexpr size_t OFF_SEL    = 0;           // alias A after k_tk: 28,311,552
static constexpr size_t OFF_FIN    = 28311552;    // alias A: bf16 conv input 194*194*192*2 = 14,451,072
static constexpr size_t OFF_WB     = 57216000;    // alias A: bf16 weights 64*9*192*2 = 221,184
static constexpr size_t OFF_TK     = 75497472;    // 75,497,472
static constexpr size_t OFF_CN     = 150994944;   // 9,437,184
static constexpr size_t OFF_QH     = 160432128;   // 4,718,592
static constexpr size_t OFF_SRCMAP = 165150720;   // 73,728
static constexpr size_t OFF_BSRC   = 165224448;   // 1,179,648
static constexpr size_t OFF_BW     = 166404096;   // 1,179,648
static constexpr size_t OFF_CSOFT  = 167583744;   // 9,216
static constexpr size_t OFF_CIDX   = 167592960;   // 9,216
static constexpr size_t OFF_CSRC   = 167602176;   // 147,456
static constexpr size_t OFF_CW     = 167749632;   // 147,456  -> total 167,897,088

__device__ inline ushort f2bf(float x) {   // round-to-nearest-even f32->bf16
  union { float f; unsigned int u; } v; v.f = x;
  unsigned int r = (v.u + 0x7FFFu + ((v.u >> 16) & 1u)) >> 16;
  return (ushort)r;
}

// ---------------- K0: nearest-neighbor source map ----------------
__global__ void k_nearmap(const float* __restrict__ loc, int* __restrict__ srcmap) {
  int idx = blockIdx.x * 256 + threadIdx.x;
  if (idx >= TT * FN) return;
  int t = idx / FN, f = idx % FN;
  float lx = loc[(size_t)(t * 2 + 0) * FN + f];
  float ly = loc[(size_t)(t * 2 + 1) * FN + f];
  float gx = 2.0f * lx / 47.0f - 1.0f;
  float gy = 2.0f * ly / 47.0f - 1.0f;
  float ix = (gx + 1.0f) * 0.5f * 47.0f;
  float iy = (gy + 1.0f) * 0.5f * 47.0f;
  int ixn = __float2int_rn(ix);
  int iyn = __float2int_rn(iy);
  bool valid = (ixn >= 0) && (ixn < 48) && (iyn >= 0) && (iyn < 48);
  srcmap[idx] = valid ? (iyn * 48 + ixn) : -1;
}

// ---------------- K1: transpose idx1 (t,cl,f) -> (t,f,cl) ----------------
__global__ __launch_bounds__(256) void k_transpose(const float* __restrict__ in, float* __restrict__ out) {
  __shared__ float tile[32][33];
  int t = blockIdx.z;
  int cl0 = blockIdx.x * 32;
  int f0 = blockIdx.y * 32;
  const float* src = in + (size_t)t * FL * FN;
  float* dst = out + (size_t)t * FN * FL;
  int tx = threadIdx.x, ty = threadIdx.y; // 32 x 8
#pragma unroll
  for (int k = 0; k < 4; k++)
    tile[ty + 8 * k][tx] = src[(size_t)(cl0 + ty + 8 * k) * FN + f0 + tx];
  __syncthreads();
#pragma unroll
  for (int k = 0; k < 4; k++)
    dst[(size_t)(f0 + ty + 8 * k) * FL + cl0 + tx] = tile[tx][ty + 8 * k];
}

// ---------------- K2: gather + L2-normalize -> tk (t,f,cl) ----------------
__global__ __launch_bounds__(256) void k_tk(const float* __restrict__ idx1t,
                                            const int* __restrict__ srcmap,
                                            float* __restrict__ tk) {
  __shared__ float red[4];
  int bid = blockIdx.x;           // t*FN + f_dst
  int t = bid / FN;
  int s = srcmap[bid];
  float* dst = tk + (size_t)bid * FL;
  int tid = threadIdx.x;
  if (s < 0) {
#pragma unroll
    for (int k = 0; k < 4; k++) dst[tid + 256 * k] = 0.f;
    return;
  }
  const float* row = idx1t + ((size_t)t * FN + s) * FL;
  float v[4];
  float sq = 0.f;
#pragma unroll
  for (int k = 0; k < 4; k++) { v[k] = row[tid + 256 * k]; sq += v[k] * v[k]; }
#pragma unroll
  for (int m = 1; m <= 32; m <<= 1) sq += __shfl_xor(sq, m, 64);
  int lane = tid & 63, w = tid >> 6;
  if (lane == 0) red[w] = sq;
  __syncthreads();
  float total = red[0] + red[1] + red[2] + red[3];
  float scale = 1.0f / fmaxf(sqrtf(total), 1e-12f);
#pragma unroll
  for (int k = 0; k < 4; k++) dst[tid + 256 * k] = v[k] * scale;
}

// ---------------- K3: unfold curr_feat + L2-normalize -> cn (f,cl) ----------------
__global__ __launch_bounds__(256) void k_cn(const float* __restrict__ cf, float* __restrict__ cn) {
  __shared__ float red[4];
  int f = blockIdx.x;             // i*48+j
  int i = f / 48, j = f % 48;
  int tid = threadIdx.x;
  float v[4];
  float sq = 0.f;
#pragma unroll
  for (int k = 0; k < 4; k++) {
    int cl = tid + 256 * k;
    int c = cl >> 4, sy = (cl >> 2) & 3, sx = cl & 3;
    v[k] = cf[(size_t)c * 36864 + (size_t)(i * 4 + sy) * 192 + (j * 4 + sx)];
    sq += v[k] * v[k];
  }
#pragma unroll
  for (int m = 1; m <= 32; m <<= 1) sq += __shfl_xor(sq, m, 64);
  int lane = tid & 63, w = tid >> 6;
  if (lane == 0) red[w] = sq;
  __syncthreads();
  float total = red[0] + red[1] + red[2] + red[3];
  float scale = 1.0f / fmaxf(sqrtf(total), 1e-12f);
#pragma unroll
  for (int k = 0; k < 4; k++) cn[(size_t)f * FL + tid + 256 * k] = v[k] * scale;
}

// ---------------- K4: q-half grouped 5x5 conv (t-invariant, per g) ----------------
__global__ __launch_bounds__(128) void k_qconv(const float* __restrict__ cn,
                                               const float* __restrict__ wtdw,
                                               const float* __restrict__ btdw,
                                               float* __restrict__ qhalf) {
  const int xt = blockIdx.x, y = blockIdx.y, g = blockIdx.z;
  const int j = threadIdx.x;      // output channel 0..127
  const int x0 = xt * 16;
  float w0[25], w1[25];
  {
    const float* wp = wtdw + (size_t)j * 50;
#pragma unroll
    for (int p = 0; p < 25; ++p) { w0[p] = wp[p]; w1[p] = wp[25 + p]; }
  }
  float acc[16];
#pragma unroll
  for (int i = 0; i < 16; ++i) acc[i] = 0.f;
  const int cbase = g * 256 + 2 * j;
#pragma unroll
  for (int r = 0; r < 5; ++r) {
    const int yy = y - 2 + r;
    if (yy < 0 || yy >= 48) continue;
#pragma unroll
    for (int cc2 = 0; cc2 < 20; ++cc2) {
      const int xx = x0 - 2 + cc2;
      float vx = 0.f, vy = 0.f;
      if (xx >= 0 && xx < 48) {
        const float2 v = *reinterpret_cast<const float2*>(cn + ((size_t)(yy * 48 + xx) << 10) + cbase);
        vx = v.x; vy = v.y;
      }
#pragma unroll
      for (int kx = 0; kx < 5; ++kx) {
        const int xo = cc2 - kx;
        if (xo >= 0 && xo < 16)
          acc[xo] = fmaf(vx, w0[r * 5 + kx], fmaf(vy, w1[r * 5 + kx], acc[xo]));
      }
    }
  }
  const float bb = btdw[j];
#pragma unroll
  for (int xo = 0; xo < 16; ++xo)
    qhalf[((size_t)g * FN + (y * 48 + x0 + xo)) * 128 + j] = acc[xo] + bb;
}

// ---------------- K5: k-half conv + LN + GELU + 1x1 + tanh + refpts -> bilinear maps ----------------
__global__ __launch_bounds__(128) void k_kconv_ln(const float* __restrict__ tk,
                                                  const float* __restrict__ wtdw,
                                                  const float* __restrict__ btdw,
                                                  const float* __restrict__ qhalf,
                                                  const float* __restrict__ lng,
                                                  const float* __restrict__ lnb,
                                                  const float* __restrict__ wtpw,
                                                  int* __restrict__ bsrc,
                                                  float* __restrict__ bw) {
  __shared__ float ch[16][257];
  const int xt = blockIdx.x, y = blockIdx.y, b = blockIdx.z;
  const int t = b >> 2, g = b & 3;
  const int j = threadIdx.x;      // output channel 128+j
  const int x0 = xt * 16;
  float w0[25], w1[25];
  {
    const float* wp = wtdw + (size_t)(128 + j) * 50;
#pragma unroll
    for (int p = 0; p < 25; ++p) { w0[p] = wp[p]; w1[p] = wp[25 + p]; }
  }
  float acc[16];
#pragma unroll
  for (int i = 0; i < 16; ++i) acc[i] = 0.f;
  const size_t tbase = (size_t)t * FN;
  const int cbase = g * 256 + 2 * j;
#pragma unroll
  for (int r = 0; r < 5; ++r) {
    const int yy = y - 2 + r;
    if (yy < 0 || yy >= 48) continue;
#pragma unroll
    for (int cc2 = 0; cc2 < 20; ++cc2) {
      const int xx = x0 - 2 + cc2;
      float vx = 0.f, vy = 0.f;
      if (xx >= 0 && xx < 48) {
        const float2 v = *reinterpret_cast<const float2*>(tk + ((tbase + yy * 48 + xx) << 10) + cbase);
        vx = v.x; vy = v.y;
      }
#pragma unroll
      for (int kx = 0; kx < 5; ++kx) {
        const int xo = cc2 - kx;
        if (xo >= 0 && xo < 16)
          acc[xo] = fmaf(vx, w0[r * 5 + kx], fmaf(vy, w1[r * 5 + kx], acc[xo]));
      }
    }
  }
  const float bb = btdw[128 + j];
#pragma unroll
  for (int xo = 0; xo < 16; ++xo) ch[xo][128 + j] = acc[xo] + bb;
#pragma unroll
  for (int xo = 0; xo < 16; ++xo)
    ch[xo][j] = qhalf[((size_t)g * FN + (y * 48 + x0 + xo)) * 128 + j];
  __syncthreads();

  const int lane = j & 63, wv = j >> 6;
  for (int p = wv; p < 16; p += 2) {
    float v0 = ch[p][lane], v1 = ch[p][lane + 64], v2 = ch[p][lane + 128], v3 = ch[p][lane + 192];
    float s = v0 + v1 + v2 + v3;
    float q = v0 * v0 + v1 * v1 + v2 * v2 + v3 * v3;
#pragma unroll
    for (int m = 1; m <= 32; m <<= 1) { s += __shfl_xor(s, m, 64); q += __shfl_xor(q, m, 64); }
    float mean = s * (1.0f / 256.0f);
    float var = q * (1.0f / 256.0f) - mean * mean;
    float rstd = rsqrtf(var + 1e-5f);
    float d0 = 0.f, d1 = 0.f;
#pragma unroll
    for (int k2 = 0; k2 < 4; k2++) {
      int c = lane + 64 * k2;
      float xv = (k2 == 0) ? v0 : (k2 == 1) ? v1 : (k2 == 2) ? v2 : v3;
      float xn = (xv - mean) * rstd * lng[c] + lnb[c];
      float ge = 0.5f * xn * (1.0f + erff(xn * 0.70710678118654752440f));
      d0 += ge * wtpw[c];
      d1 += ge * wtpw[256 + c];
    }
#pragma unroll
    for (int m = 1; m <= 32; m <<= 1) { d0 += __shfl_xor(d0, m, 64); d1 += __shfl_xor(d1, m, 64); }
    if (lane == 0) {
      float o0 = tanhf(d0) * (2.0f / 48.0f);
      float o1 = tanhf(d1) * (2.0f / 48.0f);
      int x = x0 + p;
      float ry = (0.5f + (float)y) / 48.0f * 2.0f - 1.0f;
      float rx = (0.5f + (float)x) / 48.0f * 2.0f - 1.0f;
      float pos0 = o0 + ry, pos1 = o1 + rx;   // gp = reversed
      float ix = (pos1 + 1.0f) * 0.5f * 47.0f;
      float iy = (pos0 + 1.0f) * 0.5f * 47.0f;
      float x0f = floorf(ix), y0f = floorf(iy);
      float wx = ix - x0f, wy = iy - y0f;
      int xi = (int)x0f, yi = (int)y0f;
      size_t base = ((size_t)b * FN + y * 48 + x) * 4;
#pragma unroll
      for (int c = 0; c < 4; c++) {
        int dy = c >> 1, dx = c & 1;
        int yy2 = yi + dy, xx2 = xi + dx;
        bool ok = ((unsigned)yy2 < 48u) && ((unsigned)xx2 < 48u);
        float wgt = (dy ? wy : 1.0f - wy) * (dx ? wx : 1.0f - wx);
        bsrc[base + c] = ok ? (yy2 * 48 + xx2) : -1;
        bw[base + c] = wgt;
      }
    }
  }
}

// ---------------- K6: mat einsum + max/argmax over t ----------------
__global__ __launch_bounds__(256) void k_mat(const float* __restrict__ tk,
                                             const float* __restrict__ cn,
                                             const int* __restrict__ bsrc,
                                             const float* __restrict__ bw,
                                             float* __restrict__ csoft,
                                             int* __restrict__ cidx) {
  __shared__ float cnrow[1024];
  __shared__ float red[4];
  int f = blockIdx.x;
  int tid = threadIdx.x;
#pragma unroll
  for (int k = 0; k < 4; k++) cnrow[tid + 256 * k] = cn[(size_t)f * FL + tid + 256 * k];
  __syncthreads();
  float bestv = -INFINITY;
  int besti = 0;
  for (int t = 0; t < TT; t++) {
    float partial = 0.f;
#pragma unroll
    for (int gg = 0; gg < 4; gg++) {
      int b = t * 4 + gg;
      size_t mb = ((size_t)b * FN + f) * 4;
      float v = 0.f;
#pragma unroll
      for (int c = 0; c < 4; c++) {
        int s = bsrc[mb + c];
        if (s >= 0) v += bw[mb + c] * tk[((size_t)t * FN + s) * FL + gg * 256 + tid];
      }
      partial += cnrow[gg * 256 + tid] * v;
    }
#pragma unroll
    for (int m = 1; m <= 32; m <<= 1) partial += __shfl_xor(partial, m, 64);
    int lane = tid & 63, w = tid >> 6;
    if (lane == 0) red[w] = partial;
    __syncthreads();
    if (tid == 0) {
      float tot = red[0] + red[1] + red[2] + red[3];
      if (tot > bestv) { bestv = tot; besti = t; }
    }
    __syncthreads();
  }
  if (tid == 0) { csoft[f] = bestv; cidx[f] = besti; }
}

// ---------------- K7: compose bilinear corners with nearest map at t=cidx ----------------
__global__ void k_comp(const int* __restrict__ bsrc, const float* __restrict__ bw,
                       const int* __restrict__ cidx, const int* __restrict__ srcmap,
                       int* __restrict__ csrc, float* __restrict__ cw) {
  int idx = blockIdx.x * 256 + threadIdx.x;  // f*4+g
  if (idx >= FN * 4) return;
  int f = idx >> 2, g = idx & 3;
  int t = cidx[f];
  int b = t * 4 + g;
  size_t mb = ((size_t)b * FN + f) * 4;
  size_t ob = (size_t)idx * 4;
#pragma unroll
  for (int c = 0; c < 4; c++) {
    int s = bsrc[mb + c];
    csrc[ob + c] = (s >= 0) ? srcmap[t * FN + s] : -1;
    cw[ob + c] = bw[mb + c];
  }
}

// ---------------- K8: fused nearest+bilinear+select of sparse sets ----------------
__global__ __launch_bounds__(256) void k_sel(const float* __restrict__ s1,
                                             const float* __restrict__ s2,
                                             const float* __restrict__ s3,
                                             const int* __restrict__ cidx,
                                             const int* __restrict__ csrc,
                                             const float* __restrict__ cw,
                                             float* __restrict__ sel) {
  __shared__ float pl[4 * FN];   // 4 t-planes of this channel
  int cl = blockIdx.x, m = blockIdx.y;
  const float* sm = (m == 0) ? s1 : (m == 1) ? s2 : s3;
  int g = cl >> 8;
  int tid = threadIdx.x;
  float acc[9];
  int tsel[9];
  int4 cs[9];
  float4 wv[9];
#pragma unroll
  for (int it = 0; it < 9; it++) {
    int f = tid + 256 * it;
    tsel[it] = cidx[f];
    cs[it] = *reinterpret_cast<const int4*>(csrc + ((size_t)f * 4 + g) * 4);
    wv[it] = *reinterpret_cast<const float4*>(cw + ((size_t)f * 4 + g) * 4);
    acc[it] = 0.f;
  }
  for (int half = 0; half < 2; half++) {
    __syncthreads();
    for (int i = tid; i < 4 * FN; i += 256) {
      int t = i / FN + half * 4;
      pl[i] = sm[((size_t)t * FL + cl) * FN + (i % FN)];
    }
    __syncthreads();
#pragma unroll
    for (int it = 0; it < 9; it++) {
      int t = tsel[it] - half * 4;
      if (t >= 0 && t < 4) {
        float a = 0.f;
        if (cs[it].x >= 0) a += wv[it].x * pl[t * FN + cs[it].x];
        if (cs[it].y >= 0) a += wv[it].y * pl[t * FN + cs[it].y];
        if (cs[it].z >= 0) a += wv[it].z * pl[t * FN + cs[it].z];
        if (cs[it].w >= 0) a += wv[it].w * pl[t * FN + cs[it].w];
        acc[it] = a;
      }
    }
  }
#pragma unroll
  for (int it = 0; it < 9; it++)
    sel[((size_t)m * FL + cl) * FN + tid + 256 * it] = acc[it];
}

// ---------------- K9a: zero fin borders (halo ring) ----------------
__global__ void k_zb(unsigned int* __restrict__ fin_u) {
  int idx = blockIdx.x * 256 + threadIdx.x;
  if (idx >= 772 * 96) return;
  int bp = idx / 96, u = idx % 96;
  int yy, xx;
  if (bp < 194)      { yy = 0;   xx = bp; }
  else if (bp < 388) { yy = 193; xx = bp - 194; }
  else if (bp < 580) { yy = bp - 388 + 1; xx = 0; }
  else               { yy = bp - 580 + 1; xx = 193; }
  fin_u[((size_t)yy * 194 + xx) * 96 + u] = 0;
}

// ---------------- K9b: fold + concat -> bf16 channel-last padded fin[194][194][192] ----------------
__global__ __launch_bounds__(256) void k_fold2(const float* __restrict__ sel,
                                               ushort* __restrict__ fin) {
  __shared__ float ld[256 * 49];   // 256 cl_local x 48 f_local (pad 49)
  const int fy = blockIdx.x;
  const int m = blockIdx.y >> 2, c2t = blockIdx.y & 3;
  const int t = threadIdx.x;
  const float* sp = sel + ((size_t)m * 1024 + c2t * 256) * 2304 + fy * 48;
  for (int j = 0; j < 48; j++) {
    int e = t + 256 * j;
    int cl_l = e / 48, f_l = e % 48;
    ld[cl_l * 49 + f_l] = sp[(size_t)cl_l * 2304 + f_l];
  }
  __syncthreads();
  const int ci0 = m * 64 + c2t * 16 + (t & 3) * 4;
  const int xb = t >> 2;           // 0..63
#pragma unroll
  for (int py = 0; py < 4; py++) {
    for (int jx = 0; jx < 3; jx++) {
      const int x = xb + 64 * jx;
      const int px = x & 3, fx = x >> 2;
      ushort4 v;
      ushort* vp = (ushort*)&v;
#pragma unroll
      for (int jj = 0; jj < 4; jj++) {
        int cl_l = ((t & 3) * 4 + jj) * 16 + py * 4 + px;
        vp[jj] = f2bf(ld[cl_l * 49 + fx]);
      }
      *reinterpret_cast<ushort4*>(fin + (((size_t)(fy * 4 + py + 1) * 194) + x + 1) * 192 + ci0) = v;
    }
  }
}

// ---------------- K9c: weights -> bf16 wb[co][tap][ci] ----------------
__global__ void k_wb(const float* __restrict__ wfus, ushort* __restrict__ wb) {
  int idx = blockIdx.x * 256 + threadIdx.x;   // over 64*9*96 ci-pairs
  if (idx >= 64 * 9 * 96) return;
  int cp = idx % 96, tap = (idx / 96) % 9, co = idx / (96 * 9);
  int ci = cp * 2;
  float a = wfus[((size_t)co * 192 + ci) * 9 + tap];
  float b = wfus[((size_t)co * 192 + ci + 1) * 9 + tap];
  unsigned int pk = (unsigned int)f2bf(a) | ((unsigned int)f2bf(b) << 16);
  reinterpret_cast<unsigned int*>(wb)[((size_t)co * 9 + tap) * 96 + cp] = pk;
}

// ---------------- K10: 3x3 fusion conv as bf16 MFMA implicit GEMM + *csoft_f + af ----------------
// C[64co][192x] per y-row block. 4 waves, each 48 x (3 n-tiles) x 64 co (4 m-tiles).
__global__ __launch_bounds__(256) void k_fus(const ushort* __restrict__ fin,
                                             const ushort* __restrict__ wb,
                                             const float* __restrict__ bfus,
                                             const float* __restrict__ csoft,
                                             const float* __restrict__ af,
                                             float* __restrict__ out) {
  const int y = blockIdx.x;
  const int wv = threadIdx.x >> 6;
  const int l = threadIdx.x & 63;
  const int ln = l & 15, qd = l >> 4;
  const int x0 = wv * 48;
  floatx4 acc[4][3];
#pragma unroll
  for (int a = 0; a < 4; a++)
#pragma unroll
    for (int b = 0; b < 3; b++) acc[a][b] = (floatx4){0.f, 0.f, 0.f, 0.f};

  const int koff = qd * 8;
  for (int tap = 0; tap < 9; tap++) {
    const int ky = tap / 3, kx = tap % 3;
    const ushort* brow = fin + ((size_t)(y + ky) * 194 + kx) * 192;
    const ushort* wrow = wb + (size_t)tap * 192;
#pragma unroll
    for (int c6 = 0; c6 < 6; c6++) {
      const int ci = c6 * 32 + koff;
      short8 A[4], B[3];
#pragma unroll
      for (int mt = 0; mt < 4; mt++)
        A[mt] = *reinterpret_cast<const short8*>(wrow + (size_t)(mt * 16 + ln) * 1728 + ci);
#pragma unroll
      for (int nt = 0; nt < 3; nt++)
        B[nt] = *reinterpret_cast<const short8*>(brow + (size_t)(x0 + nt * 16 + ln) * 192 + ci);
#pragma unroll
      for (int mt = 0; mt < 4; mt++)
#pragma unroll
        for (int nt = 0; nt < 3; nt++)
          acc[mt][nt] = __builtin_amdgcn_mfma_f32_16x16x32_bf16(A[mt], B[nt], acc[mt][nt], 0, 0, 0);
    }
  }
#pragma unroll
  for (int nt = 0; nt < 3; nt++) {
    const int x = x0 + nt * 16 + ln;
    const float cs = csoft[(y >> 2) * 48 + (x >> 2)];
#pragma unroll
    for (int mt = 0; mt < 4; mt++) {
#pragma unroll
      for (int r = 0; r < 4; r++) {
        const int co = mt * 16 + qd * 4 + r;
        const size_t oi = (size_t)co * 36864 + (size_t)y * 192 + x;
        out[oi] = (acc[mt][nt][r] + bfus[co]) * cs + af[oi];
      }
    }
  }
}

// ---------------- launcher ----------------
extern "C" void kernel_launch(void* const* d_in, const int* in_sizes, int n_in,
                              void* d_out, int out_size, void* d_ws, size_t ws_size,
                              hipStream_t stream) {
  const float* cf   = (const float*)d_in[0];
  const float* idx1 = (const float*)d_in[1];
  const float* af   = (const float*)d_in[2];
  const float* s1   = (const float*)d_in[3];
  const float* s2   = (const float*)d_in[4];
  const float* s3   = (const float*)d_in[5];
  const float* loc  = (const float*)d_in[6];
  const float* wtdw = (const float*)d_in[7];
  const float* btdw = (const float*)d_in[8];
  const float* lng  = (const float*)d_in[9];
  const float* lnb  = (const float*)d_in[10];
  const float* wtpw = (const float*)d_in[11];
  const float* wfus = (const float*)d_in[12];
  const float* bfus = (const float*)d_in[13];
  float* out = (float*)d_out;
  char* ws = (char*)d_ws;

  float* idx1t  = (float*)(ws + OFF_IDX1T);
  float* sel    = (float*)(ws + OFF_SEL);
  ushort* fin   = (ushort*)(ws + OFF_FIN);
  ushort* wb    = (ushort*)(ws + OFF_WB);
  float* tk     = (float*)(ws + OFF_TK);
  float* cn     = (float*)(ws + OFF_CN);
  float* qh     = (float*)(ws + OFF_QH);
  int*   srcmap = (int*)(ws + OFF_SRCMAP);
  int*   bsrc   = (int*)(ws + OFF_BSRC);
  float* bw     = (float*)(ws + OFF_BW);
  float* csoft  = (float*)(ws + OFF_CSOFT);
  int*   cidx   = (int*)(ws + OFF_CIDX);
  int*   csrc   = (int*)(ws + OFF_CSRC);
  float* cw     = (float*)(ws + OFF_CW);

  k_nearmap<<<72, 256, 0, stream>>>(loc, srcmap);
  k_transpose<<<dim3(32, 72, 8), dim3(32, 8), 0, stream>>>(idx1, idx1t);
  k_cn<<<2304, 256, 0, stream>>>(cf, cn);
  k_tk<<<18432, 256, 0, stream>>>(idx1t, srcmap, tk);
  // region A (idx1t) dead from here; aliased by sel / fin / wb
  k_wb<<<216, 256, 0, stream>>>(wfus, wb);
  k_zb<<<290, 256, 0, stream>>>((unsigned int*)fin);
  k_qconv<<<dim3(3, 48, 4), 128, 0, stream>>>(cn, wtdw, btdw, qh);
  k_kconv_ln<<<dim3(3, 48, 32), 128, 0, stream>>>(tk, wtdw, btdw, qh, lng, lnb, wtpw, bsrc, bw);
  k_mat<<<2304, 256, 0, stream>>>(tk, cn, bsrc, bw, csoft, cidx);
  k_comp<<<36, 256, 0, stream>>>(bsrc, bw, cidx, srcmap, csrc, cw);
  k_sel<<<dim3(1024, 3), 256, 0, stream>>>(s1, s2, s3, cidx, csrc, cw, sel);
  k_fold2<<<dim3(48, 12), 256, 0, stream>>>(sel, fin);
  k_fus<<<192, 256, 0, stream>>>(fin, wb, bfus, csoft, af, out);
}

// Round 3
// 546.827 us; speedup vs baseline: 1.5654x; 1.1436x over previous
//
#include <hip/hip_runtime.h>
#include <math.h>

// Problem constants
#define TT 8
#define FN 2304          // 48*48
#define FL 1024          // C*S*S
#define HS 48

typedef __attribute__((ext_vector_type(8))) short short8;
typedef __attribute__((ext_vector_type(4))) float floatx4;

// ---------------- workspace layout (bytes) ----------------
static constexpr size_t OFF_IDX1T  = 0;           // 75,497,472 (region A)
static constexpr size_t OFF_SEL    = 0;           // alias A after k_tk: 28,311,552
static constexpr size_t OFF_FIN    = 28311552;    // alias A: bf16 conv input 194*194*192*2 = 14,451,072
static constexpr size_t OFF_WB     = 57216000;    // alias A: bf16 weights 64*9*192*2 = 221,184
static constexpr size_t OFF_TK     = 75497472;    // 75,497,472
static constexpr size_t OFF_CN     = 150994944;   // 9,437,184
static constexpr size_t OFF_QH     = 160432128;   // 4,718,592
static constexpr size_t OFF_SRCMAP = 165150720;   // 73,728
static constexpr size_t OFF_BSRC   = 165224448;   // 1,179,648
static constexpr size_t OFF_BW     = 166404096;   // 1,179,648
static constexpr size_t OFF_CSOFT  = 167583744;   // 9,216
static constexpr size_t OFF_CIDX   = 167592960;   // 9,216
static constexpr size_t OFF_CSRC   = 167602176;   // 147,456
static constexpr size_t OFF_CW     = 167749632;   // 147,456  -> total 167,897,088

__device__ inline ushort f2bf(float x) {   // round-to-nearest-even f32->bf16
  union { float f; unsigned int u; } v; v.f = x;
  unsigned int r = (v.u + 0x7FFFu + ((v.u >> 16) & 1u)) >> 16;
  return (ushort)r;
}

// ---------------- K0: nearest-neighbor source map ----------------
__global__ void k_nearmap(const float* __restrict__ loc, int* __restrict__ srcmap) {
  int idx = blockIdx.x * 256 + threadIdx.x;
  if (idx >= TT * FN) return;
  int t = idx / FN, f = idx % FN;
  float lx = loc[(size_t)(t * 2 + 0) * FN + f];
  float ly = loc[(size_t)(t * 2 + 1) * FN + f];
  float gx = 2.0f * lx / 47.0f - 1.0f;
  float gy = 2.0f * ly / 47.0f - 1.0f;
  float ix = (gx + 1.0f) * 0.5f * 47.0f;
  float iy = (gy + 1.0f) * 0.5f * 47.0f;
  int ixn = __float2int_rn(ix);
  int iyn = __float2int_rn(iy);
  bool valid = (ixn >= 0) && (ixn < 48) && (iyn >= 0) && (iyn < 48);
  srcmap[idx] = valid ? (iyn * 48 + ixn) : -1;
}

// ---------------- K1: transpose idx1 (t,cl,f) -> (t,f,cl), 64x64 float4 tiles ----------------
__global__ __launch_bounds__(256) void k_transpose(const float* __restrict__ in, float* __restrict__ out) {
  __shared__ float tile[64][65];
  const int t = blockIdx.z;
  const int cl0 = blockIdx.x * 64;   // 16 tiles
  const int f0 = blockIdx.y * 64;    // 36 tiles
  const float* src = in + (size_t)t * FL * FN;
  float* dst = out + (size_t)t * FN * FL;
  const int tx = threadIdx.x & 15, ty = threadIdx.x >> 4;  // 16 x 16
#pragma unroll
  for (int k = 0; k < 4; k++) {
    const float4 v = *reinterpret_cast<const float4*>(src + (size_t)(cl0 + ty + 16 * k) * FN + f0 + tx * 4);
    float* tr = &tile[ty + 16 * k][tx * 4];
    tr[0] = v.x; tr[1] = v.y; tr[2] = v.z; tr[3] = v.w;
  }
  __syncthreads();
#pragma unroll
  for (int k = 0; k < 4; k++) {
    float4 v;
    v.x = tile[tx * 4 + 0][ty + 16 * k];
    v.y = tile[tx * 4 + 1][ty + 16 * k];
    v.z = tile[tx * 4 + 2][ty + 16 * k];
    v.w = tile[tx * 4 + 3][ty + 16 * k];
    *reinterpret_cast<float4*>(dst + (size_t)(f0 + ty + 16 * k) * FL + cl0 + tx * 4) = v;
  }
}

// ---------------- K2: gather + L2-normalize -> tk (t,f,cl), float4 ----------------
__global__ __launch_bounds__(256) void k_tk(const float* __restrict__ idx1t,
                                            const int* __restrict__ srcmap,
                                            float* __restrict__ tk) {
  __shared__ float red[4];
  const int bid = blockIdx.x;           // t*FN + f_dst
  const int t = bid / FN;
  const int s = srcmap[bid];
  float4* dst = reinterpret_cast<float4*>(tk + (size_t)bid * FL);
  const int tid = threadIdx.x;
  if (s < 0) {
    dst[tid] = make_float4(0.f, 0.f, 0.f, 0.f);
    return;
  }
  const float4* row = reinterpret_cast<const float4*>(idx1t + ((size_t)t * FN + s) * FL);
  float4 v = row[tid];
  float sq = v.x * v.x + v.y * v.y + v.z * v.z + v.w * v.w;
#pragma unroll
  for (int m = 1; m <= 32; m <<= 1) sq += __shfl_xor(sq, m, 64);
  const int lane = tid & 63, w = tid >> 6;
  if (lane == 0) red[w] = sq;
  __syncthreads();
  const float total = red[0] + red[1] + red[2] + red[3];
  const float scale = 1.0f / fmaxf(sqrtf(total), 1e-12f);
  dst[tid] = make_float4(v.x * scale, v.y * scale, v.z * scale, v.w * scale);
}

// ---------------- K3: unfold curr_feat + L2-normalize -> cn (f,cl) ----------------
__global__ __launch_bounds__(256) void k_cn(const float* __restrict__ cf, float* __restrict__ cn) {
  __shared__ float red[4];
  int f = blockIdx.x;             // i*48+j
  int i = f / 48, j = f % 48;
  int tid = threadIdx.x;
  float v[4];
  float sq = 0.f;
#pragma unroll
  for (int k = 0; k < 4; k++) {
    int cl = tid + 256 * k;
    int c = cl >> 4, sy = (cl >> 2) & 3, sx = cl & 3;
    v[k] = cf[(size_t)c * 36864 + (size_t)(i * 4 + sy) * 192 + (j * 4 + sx)];
    sq += v[k] * v[k];
  }
#pragma unroll
  for (int m = 1; m <= 32; m <<= 1) sq += __shfl_xor(sq, m, 64);
  int lane = tid & 63, w = tid >> 6;
  if (lane == 0) red[w] = sq;
  __syncthreads();
  float total = red[0] + red[1] + red[2] + red[3];
  float scale = 1.0f / fmaxf(sqrtf(total), 1e-12f);
#pragma unroll
  for (int k = 0; k < 4; k++) cn[(size_t)f * FL + tid + 256 * k] = v[k] * scale;
}

// ---------------- K4: q-half grouped 5x5 conv (t-invariant, per g) ----------------
__global__ __launch_bounds__(128) void k_qconv(const float* __restrict__ cn,
                                               const float* __restrict__ wtdw,
                                               const float* __restrict__ btdw,
                                               float* __restrict__ qhalf) {
  const int xt = blockIdx.x, y = blockIdx.y, g = blockIdx.z;
  const int j = threadIdx.x;      // output channel 0..127
  const int x0 = xt * 16;
  float w0[25], w1[25];
  {
    const float* wp = wtdw + (size_t)j * 50;
#pragma unroll
    for (int p = 0; p < 25; ++p) { w0[p] = wp[p]; w1[p] = wp[25 + p]; }
  }
  float acc[16];
#pragma unroll
  for (int i = 0; i < 16; ++i) acc[i] = 0.f;
  const int cbase = g * 256 + 2 * j;
#pragma unroll
  for (int r = 0; r < 5; ++r) {
    const int yy = y - 2 + r;
    if (yy < 0 || yy >= 48) continue;
#pragma unroll
    for (int cc2 = 0; cc2 < 20; ++cc2) {
      const int xx = x0 - 2 + cc2;
      float vx = 0.f, vy = 0.f;
      if (xx >= 0 && xx < 48) {
        const float2 v = *reinterpret_cast<const float2*>(cn + ((size_t)(yy * 48 + xx) << 10) + cbase);
        vx = v.x; vy = v.y;
      }
#pragma unroll
      for (int kx = 0; kx < 5; ++kx) {
        const int xo = cc2 - kx;
        if (xo >= 0 && xo < 16)
          acc[xo] = fmaf(vx, w0[r * 5 + kx], fmaf(vy, w1[r * 5 + kx], acc[xo]));
      }
    }
  }
  const float bb = btdw[j];
#pragma unroll
  for (int xo = 0; xo < 16; ++xo)
    qhalf[((size_t)g * FN + (y * 48 + x0 + xo)) * 128 + j] = acc[xo] + bb;
}

// ---------------- K5: k-half conv + LN + GELU + 1x1 + tanh + refpts -> bilinear maps ----------------
__global__ __launch_bounds__(128) void k_kconv_ln(const float* __restrict__ tk,
                                                  const float* __restrict__ wtdw,
                                                  const float* __restrict__ btdw,
                                                  const float* __restrict__ qhalf,
                                                  const float* __restrict__ lng,
                                                  const float* __restrict__ lnb,
                                                  const float* __restrict__ wtpw,
                                                  int* __restrict__ bsrc,
                                                  float* __restrict__ bw) {
  __shared__ float ch[16][257];
  const int xt = blockIdx.x, y = blockIdx.y, b = blockIdx.z;
  const int t = b >> 2, g = b & 3;
  const int j = threadIdx.x;      // output channel 128+j
  const int x0 = xt * 16;
  float w0[25], w1[25];
  {
    const float* wp = wtdw + (size_t)(128 + j) * 50;
#pragma unroll
    for (int p = 0; p < 25; ++p) { w0[p] = wp[p]; w1[p] = wp[25 + p]; }
  }
  float acc[16];
#pragma unroll
  for (int i = 0; i < 16; ++i) acc[i] = 0.f;
  const size_t tbase = (size_t)t * FN;
  const int cbase = g * 256 + 2 * j;
#pragma unroll
  for (int r = 0; r < 5; ++r) {
    const int yy = y - 2 + r;
    if (yy < 0 || yy >= 48) continue;
#pragma unroll
    for (int cc2 = 0; cc2 < 20; ++cc2) {
      const int xx = x0 - 2 + cc2;
      float vx = 0.f, vy = 0.f;
      if (xx >= 0 && xx < 48) {
        const float2 v = *reinterpret_cast<const float2*>(tk + ((tbase + yy * 48 + xx) << 10) + cbase);
        vx = v.x; vy = v.y;
      }
#pragma unroll
      for (int kx = 0; kx < 5; ++kx) {
        const int xo = cc2 - kx;
        if (xo >= 0 && xo < 16)
          acc[xo] = fmaf(vx, w0[r * 5 + kx], fmaf(vy, w1[r * 5 + kx], acc[xo]));
      }
    }
  }
  const float bb = btdw[128 + j];
#pragma unroll
  for (int xo = 0; xo < 16; ++xo) ch[xo][128 + j] = acc[xo] + bb;
#pragma unroll
  for (int xo = 0; xo < 16; ++xo)
    ch[xo][j] = qhalf[((size_t)g * FN + (y * 48 + x0 + xo)) * 128 + j];
  __syncthreads();

  const int lane = j & 63, wv = j >> 6;
  for (int p = wv; p < 16; p += 2) {
    float v0 = ch[p][lane], v1 = ch[p][lane + 64], v2 = ch[p][lane + 128], v3 = ch[p][lane + 192];
    float s = v0 + v1 + v2 + v3;
    float q = v0 * v0 + v1 * v1 + v2 * v2 + v3 * v3;
#pragma unroll
    for (int m = 1; m <= 32; m <<= 1) { s += __shfl_xor(s, m, 64); q += __shfl_xor(q, m, 64); }
    float mean = s * (1.0f / 256.0f);
    float var = q * (1.0f / 256.0f) - mean * mean;
    float rstd = rsqrtf(var + 1e-5f);
    float d0 = 0.f, d1 = 0.f;
#pragma unroll
    for (int k2 = 0; k2 < 4; k2++) {
      int c = lane + 64 * k2;
      float xv = (k2 == 0) ? v0 : (k2 == 1) ? v1 : (k2 == 2) ? v2 : v3;
      float xn = (xv - mean) * rstd * lng[c] + lnb[c];
      float ge = 0.5f * xn * (1.0f + erff(xn * 0.70710678118654752440f));
      d0 += ge * wtpw[c];
      d1 += ge * wtpw[256 + c];
    }
#pragma unroll
    for (int m = 1; m <= 32; m <<= 1) { d0 += __shfl_xor(d0, m, 64); d1 += __shfl_xor(d1, m, 64); }
    if (lane == 0) {
      float o0 = tanhf(d0) * (2.0f / 48.0f);
      float o1 = tanhf(d1) * (2.0f / 48.0f);
      int x = x0 + p;
      float ry = (0.5f + (float)y) / 48.0f * 2.0f - 1.0f;
      float rx = (0.5f + (float)x) / 48.0f * 2.0f - 1.0f;
      float pos0 = o0 + ry, pos1 = o1 + rx;   // gp = reversed
      float ix = (pos1 + 1.0f) * 0.5f * 47.0f;
      float iy = (pos0 + 1.0f) * 0.5f * 47.0f;
      float x0f = floorf(ix), y0f = floorf(iy);
      float wx = ix - x0f, wy = iy - y0f;
      int xi = (int)x0f, yi = (int)y0f;
      size_t base = ((size_t)b * FN + y * 48 + x) * 4;
#pragma unroll
      for (int c = 0; c < 4; c++) {
        int dy = c >> 1, dx = c & 1;
        int yy2 = yi + dy, xx2 = xi + dx;
        bool ok = ((unsigned)yy2 < 48u) && ((unsigned)xx2 < 48u);
        float wgt = (dy ? wy : 1.0f - wy) * (dx ? wx : 1.0f - wx);
        bsrc[base + c] = ok ? (yy2 * 48 + xx2) : -1;
        bw[base + c] = wgt;
      }
    }
  }
}

// ---------------- K6: mat einsum + max/argmax over t (float4) ----------------
__global__ __launch_bounds__(256) void k_mat(const float* __restrict__ tk,
                                             const float* __restrict__ cn,
                                             const int* __restrict__ bsrc,
                                             const float* __restrict__ bw,
                                             float* __restrict__ csoft,
                                             int* __restrict__ cidx) {
  __shared__ float red[8][4];
  const int f = blockIdx.x;
  const int tid = threadIdx.x;
  const int lane = tid & 63, w = tid >> 6;   // w == channel group gg
  const int coff = w * 256 + lane * 4;
  const float4 cnv = *reinterpret_cast<const float4*>(cn + (size_t)f * FL + coff);
#pragma unroll
  for (int t = 0; t < TT; t++) {
    const size_t mb = ((size_t)(t * 4 + w) * FN + f) * 4;
    const int4 cs = *reinterpret_cast<const int4*>(bsrc + mb);
    const float4 wv = *reinterpret_cast<const float4*>(bw + mb);
    float ax = 0.f, ay = 0.f, az = 0.f, aw = 0.f;
    const float* tkt = tk + (size_t)t * FN * FL + coff;
    if (cs.x >= 0) { const float4 u = *reinterpret_cast<const float4*>(tkt + ((size_t)cs.x << 10)); ax = fmaf(wv.x, u.x, ax); ay = fmaf(wv.x, u.y, ay); az = fmaf(wv.x, u.z, az); aw = fmaf(wv.x, u.w, aw); }
    if (cs.y >= 0) { const float4 u = *reinterpret_cast<const float4*>(tkt + ((size_t)cs.y << 10)); ax = fmaf(wv.y, u.x, ax); ay = fmaf(wv.y, u.y, ay); az = fmaf(wv.y, u.z, az); aw = fmaf(wv.y, u.w, aw); }
    if (cs.z >= 0) { const float4 u = *reinterpret_cast<const float4*>(tkt + ((size_t)cs.z << 10)); ax = fmaf(wv.z, u.x, ax); ay = fmaf(wv.z, u.y, ay); az = fmaf(wv.z, u.z, az); aw = fmaf(wv.z, u.w, aw); }
    if (cs.w >= 0) { const float4 u = *reinterpret_cast<const float4*>(tkt + ((size_t)cs.w << 10)); ax = fmaf(wv.w, u.x, ax); ay = fmaf(wv.w, u.y, ay); az = fmaf(wv.w, u.z, az); aw = fmaf(wv.w, u.w, aw); }
    float partial = ax * cnv.x + ay * cnv.y + az * cnv.z + aw * cnv.w;
#pragma unroll
    for (int m = 1; m <= 32; m <<= 1) partial += __shfl_xor(partial, m, 64);
    if (lane == 0) red[t][w] = partial;
  }
  __syncthreads();
  if (tid == 0) {
    float bestv = -INFINITY;
    int besti = 0;
#pragma unroll
    for (int t = 0; t < TT; t++) {
      float tot = red[t][0] + red[t][1] + red[t][2] + red[t][3];
      if (tot > bestv) { bestv = tot; besti = t; }
    }
    csoft[f] = bestv; cidx[f] = besti;
  }
}

// ---------------- K7: compose bilinear corners with nearest map at t=cidx ----------------
__global__ void k_comp(const int* __restrict__ bsrc, const float* __restrict__ bw,
                       const int* __restrict__ cidx, const int* __restrict__ srcmap,
                       int* __restrict__ csrc, float* __restrict__ cw) {
  int idx = blockIdx.x * 256 + threadIdx.x;  // f*4+g
  if (idx >= FN * 4) return;
  int f = idx >> 2, g = idx & 3;
  int t = cidx[f];
  int b = t * 4 + g;
  size_t mb = ((size_t)b * FN + f) * 4;
  size_t ob = (size_t)idx * 4;
#pragma unroll
  for (int c = 0; c < 4; c++) {
    int s = bsrc[mb + c];
    csrc[ob + c] = (s >= 0) ? srcmap[t * FN + s] : -1;
    cw[ob + c] = bw[mb + c];
  }
}

// ---------------- K8: fused nearest+bilinear+select of sparse sets (float4 stream) ----------------
__global__ __launch_bounds__(256) void k_sel(const float* __restrict__ s1,
                                             const float* __restrict__ s2,
                                             const float* __restrict__ s3,
                                             const int* __restrict__ cidx,
                                             const int* __restrict__ csrc,
                                             const float* __restrict__ cw,
                                             float* __restrict__ sel) {
  __shared__ float pl[4 * FN];   // 4 t-planes of this channel, 36,864 B
  const int cl = blockIdx.x, m = blockIdx.y;
  const float* sm = (m == 0) ? s1 : (m == 1) ? s2 : s3;
  const int g = cl >> 8;
  const int tid = threadIdx.x;
  float acc[9];
  int tsel[9];
  int4 cs[9];
  float4 wv[9];
#pragma unroll
  for (int it = 0; it < 9; it++) {
    int f = tid + 256 * it;
    tsel[it] = cidx[f];
    cs[it] = *reinterpret_cast<const int4*>(csrc + ((size_t)f * 4 + g) * 4);
    wv[it] = *reinterpret_cast<const float4*>(cw + ((size_t)f * 4 + g) * 4);
    acc[it] = 0.f;
  }
  float4* pl4 = reinterpret_cast<float4*>(pl);
  for (int half = 0; half < 2; half++) {
    __syncthreads();
#pragma unroll
    for (int j = 0; j < 9; j++) {             // 2304 float4 over 256 threads
      const int e = j * 256 + tid;
      const int tl = e / 576;                 // plane 0..3
      const int r = e - tl * 576;
      const float4* src4 = reinterpret_cast<const float4*>(sm + ((size_t)(half * 4 + tl) * FL + cl) * FN);
      pl4[e] = src4[r];
    }
    __syncthreads();
#pragma unroll
    for (int it = 0; it < 9; it++) {
      const int t = tsel[it] - half * 4;
      if (t >= 0 && t < 4) {
        float a = 0.f;
        if (cs[it].x >= 0) a += wv[it].x * pl[t * FN + cs[it].x];
        if (cs[it].y >= 0) a += wv[it].y * pl[t * FN + cs[it].y];
        if (cs[it].z >= 0) a += wv[it].z * pl[t * FN + cs[it].z];
        if (cs[it].w >= 0) a += wv[it].w * pl[t * FN + cs[it].w];
        acc[it] = a;
      }
    }
  }
  // re-pack through LDS for float4 row stores
  __syncthreads();
#pragma unroll
  for (int it = 0; it < 9; it++) pl[tid + 256 * it] = acc[it];
  __syncthreads();
  float4* orow = reinterpret_cast<float4*>(sel + ((size_t)m * FL + cl) * FN);
#pragma unroll
  for (int e = tid; e < 576; e += 256) orow[e] = pl4[e];
}

// ---------------- K9a: zero fin borders (halo ring) ----------------
__global__ void k_zb(unsigned int* __restrict__ fin_u) {
  int idx = blockIdx.x * 256 + threadIdx.x;
  if (idx >= 772 * 96) return;
  int bp = idx / 96, u = idx % 96;
  int yy, xx;
  if (bp < 194)      { yy = 0;   xx = bp; }
  else if (bp < 388) { yy = 193; xx = bp - 194; }
  else if (bp < 580) { yy = bp - 388 + 1; xx = 0; }
  else               { yy = bp - 580 + 1; xx = 193; }
  fin_u[((size_t)yy * 194 + xx) * 96 + u] = 0;
}

// ---------------- K9b: fold + concat -> bf16 channel-last padded fin[194][194][192] ----------------
__global__ __launch_bounds__(256) void k_fold2(const float* __restrict__ sel,
                                               ushort* __restrict__ fin) {
  __shared__ float ld[256 * 49];   // 256 cl_local x 48 f_local (pad 49)
  const int fy = blockIdx.x;
  const int m = blockIdx.y >> 2, c2t = blockIdx.y & 3;
  const int t = threadIdx.x;
  const float* sp = sel + ((size_t)m * 1024 + c2t * 256) * 2304 + fy * 48;
#pragma unroll
  for (int j = 0; j < 12; j++) {             // 3072 float4 = 256 rows x 12
    const int e = t + 256 * j;
    const int cl_l = e / 12, c4 = e % 12;
    const float4 v = *reinterpret_cast<const float4*>(sp + (size_t)cl_l * 2304 + c4 * 4);
    float* dr = &ld[cl_l * 49 + c4 * 4];
    dr[0] = v.x; dr[1] = v.y; dr[2] = v.z; dr[3] = v.w;
  }
  __syncthreads();
  const int ci0 = m * 64 + c2t * 16 + (t & 3) * 4;
  const int xb = t >> 2;           // 0..63
#pragma unroll
  for (int py = 0; py < 4; py++) {
    for (int jx = 0; jx < 3; jx++) {
      const int x = xb + 64 * jx;
      const int px = x & 3, fx = x >> 2;
      ushort4 v;
      ushort* vp = (ushort*)&v;
#pragma unroll
      for (int jj = 0; jj < 4; jj++) {
        int cl_l = ((t & 3) * 4 + jj) * 16 + py * 4 + px;
        vp[jj] = f2bf(ld[cl_l * 49 + fx]);
      }
      *reinterpret_cast<ushort4*>(fin + (((size_t)(fy * 4 + py + 1) * 194) + x + 1) * 192 + ci0) = v;
    }
  }
}

// ---------------- K9c: weights -> bf16 wb[co][tap][ci] ----------------
__global__ void k_wb(const float* __restrict__ wfus, ushort* __restrict__ wb) {
  int idx = blockIdx.x * 256 + threadIdx.x;   // over 64*9*96 ci-pairs
  if (idx >= 64 * 9 * 96) return;
  int cp = idx % 96, tap = (idx / 96) % 9, co = idx / (96 * 9);
  int ci = cp * 2;
  float a = wfus[((size_t)co * 192 + ci) * 9 + tap];
  float b = wfus[((size_t)co * 192 + ci + 1) * 9 + tap];
  unsigned int pk = (unsigned int)f2bf(a) | ((unsigned int)f2bf(b) << 16);
  reinterpret_cast<unsigned int*>(wb)[((size_t)co * 9 + tap) * 96 + cp] = pk;
}

// ---------------- K10: 3x3 fusion conv as bf16 MFMA implicit GEMM + *csoft_f + af ----------------
__global__ __launch_bounds__(256) void k_fus(const ushort* __restrict__ fin,
                                             const ushort* __restrict__ wb,
                                             const float* __restrict__ bfus,
                                             const float* __restrict__ csoft,
                                             const float* __restrict__ af,
                                             float* __restrict__ out) {
  const int y = blockIdx.x;
  const int wv = threadIdx.x >> 6;
  const int l = threadIdx.x & 63;
  const int ln = l & 15, qd = l >> 4;
  const int x0 = wv * 48;
  floatx4 acc[4][3];
#pragma unroll
  for (int a = 0; a < 4; a++)
#pragma unroll
    for (int b = 0; b < 3; b++) acc[a][b] = (floatx4){0.f, 0.f, 0.f, 0.f};

  const int koff = qd * 8;
  for (int tap = 0; tap < 9; tap++) {
    const int ky = tap / 3, kx = tap % 3;
    const ushort* brow = fin + ((size_t)(y + ky) * 194 + kx) * 192;
    const ushort* wrow = wb + (size_t)tap * 192;
#pragma unroll
    for (int c6 = 0; c6 < 6; c6++) {
      const int ci = c6 * 32 + koff;
      short8 A[4], B[3];
#pragma unroll
      for (int mt = 0; mt < 4; mt++)
        A[mt] = *reinterpret_cast<const short8*>(wrow + (size_t)(mt * 16 + ln) * 1728 + ci);
#pragma unroll
      for (int nt = 0; nt < 3; nt++)
        B[nt] = *reinterpret_cast<const short8*>(brow + (size_t)(x0 + nt * 16 + ln) * 192 + ci);
#pragma unroll
      for (int mt = 0; mt < 4; mt++)
#pragma unroll
        for (int nt = 0; nt < 3; nt++)
          acc[mt][nt] = __builtin_amdgcn_mfma_f32_16x16x32_bf16(A[mt], B[nt], acc[mt][nt], 0, 0, 0);
    }
  }
#pragma unroll
  for (int nt = 0; nt < 3; nt++) {
    const int x = x0 + nt * 16 + ln;
    const float cs = csoft[(y >> 2) * 48 + (x >> 2)];
#pragma unroll
    for (int mt = 0; mt < 4; mt++) {
#pragma unroll
      for (int r = 0; r < 4; r++) {
        const int co = mt * 16 + qd * 4 + r;
        const size_t oi = (size_t)co * 36864 + (size_t)y * 192 + x;
        out[oi] = (acc[mt][nt][r] + bfus[co]) * cs + af[oi];
      }
    }
  }
}

// ---------------- launcher ----------------
extern "C" void kernel_launch(void* const* d_in, const int* in_sizes, int n_in,
                              void* d_out, int out_size, void* d_ws, size_t ws_size,
                              hipStream_t stream) {
  const float* cf   = (const float*)d_in[0];
  const float* idx1 = (const float*)d_in[1];
  const float* af   = (const float*)d_in[2];
  const float* s1   = (const float*)d_in[3];
  const float* s2   = (const float*)d_in[4];
  const float* s3   = (const float*)d_in[5];
  const float* loc  = (const float*)d_in[6];
  const float* wtdw = (const float*)d_in[7];
  const float* btdw = (const float*)d_in[8];
  const float* lng  = (const float*)d_in[9];
  const float* lnb  = (const float*)d_in[10];
  const float* wtpw = (const float*)d_in[11];
  const float* wfus = (const float*)d_in[12];
  const float* bfus = (const float*)d_in[13];
  float* out = (float*)d_out;
  char* ws = (char*)d_ws;

  float* idx1t  = (float*)(ws + OFF_IDX1T);
  float* sel    = (float*)(ws + OFF_SEL);
  ushort* fin   = (ushort*)(ws + OFF_FIN);
  ushort* wb    = (ushort*)(ws + OFF_WB);
  float* tk     = (float*)(ws + OFF_TK);
  float* cn     = (float*)(ws + OFF_CN);
  float* qh     = (float*)(ws + OFF_QH);
  int*   srcmap = (int*)(ws + OFF_SRCMAP);
  int*   bsrc   = (int*)(ws + OFF_BSRC);
  float* bw     = (float*)(ws + OFF_BW);
  float* csoft  = (float*)(ws + OFF_CSOFT);
  int*   cidx   = (int*)(ws + OFF_CIDX);
  int*   csrc   = (int*)(ws + OFF_CSRC);
  float* cw     = (float*)(ws + OFF_CW);

  k_nearmap<<<72, 256, 0, stream>>>(loc, srcmap);
  k_transpose<<<dim3(16, 36, 8), 256, 0, stream>>>(idx1, idx1t);
  k_cn<<<2304, 256, 0, stream>>>(cf, cn);
  k_tk<<<18432, 256, 0, stream>>>(idx1t, srcmap, tk);
  // region A (idx1t) dead from here; aliased by sel / fin / wb
  k_wb<<<216, 256, 0, stream>>>(wfus, wb);
  k_zb<<<290, 256, 0, stream>>>((unsigned int*)fin);
  k_qconv<<<dim3(3, 48, 4), 128, 0, stream>>>(cn, wtdw, btdw, qh);
  k_kconv_ln<<<dim3(3, 48, 32), 128, 0, stream>>>(tk, wtdw, btdw, qh, lng, lnb, wtpw, bsrc, bw);
  k_mat<<<2304, 256, 0, stream>>>(tk, cn, bsrc, bw, csoft, cidx);
  k_comp<<<36, 256, 0, stream>>>(bsrc, bw, cidx, srcmap, csrc, cw);
  k_sel<<<dim3(1024, 3), 256, 0, stream>>>(s1, s2, s3, cidx, csrc, cw, sel);
  k_fold2<<<dim3(48, 12), 256, 0, stream>>>(sel, fin);
  k_fus<<<192, 256, 0, stream>>>(fin, wb, bfus, csoft, af, out);
}